// Round 16
// baseline (110.968 us; speedup 1.0000x reference)
//
#include <hip/hip_runtime.h>
#include <math.h>

#define NT 1024
#define PW 66      // padded LDS row stride
#define RR 52      // LDS buffer rows (52 X rows / 50 r rows / 48 v rows + ring)

// Pin to AGPR (unified file) — frees arch VGPRs for window/weights/temps.
#define AW(arr, idx, val) asm("v_accvgpr_write_b32 %0, %1" : "=a"(arr[idx]) : "v"(val))
#define AR(dst, arr, idx) asm("v_accvgpr_read_b32 %0, %1" : "=v"(dst) : "a"(arr[idx]))

// Two launches: chunk<15,FIRST> then chunk<14,LAST>. 256 blocks (1 per CU),
// block = half image (32 core rows + 16-row internal halo; 48 v-rows).
// Geometry (r14/r15, best): lane owns ONE column (c=tid&63) and THREE cell rows
// (ty=tid>>6), all 16 channels in-lane; weights in LDS (2xb128+b32 per channel);
// rq[48] AGPR-pinned. r16 deltas: (1) !FIRST prologue stages r from out_r
// (bitwise-identical to recompute; launch-1 wrote it) — skips X staging,
// 150-ch collapse, r-conv, and 2 barriers; (2) channel-paired max -> v_max3
// (15 -> 8 max ops per cell, exact).
template<int NIT, bool FIRST, bool LAST>
__global__ __launch_bounds__(NT)
void vin_chunk(const float* __restrict__ layout,
               const float* __restrict__ heatmap,
               const float* __restrict__ h_w,
               const float* __restrict__ h_b,
               const float* __restrict__ r_w,
               const float* __restrict__ q_w,
               const float* __restrict__ w,
               const float* __restrict__ fc_w,
               const int* __restrict__ S1,
               const int* __restrict__ S2,
               float* __restrict__ vg,
               float* __restrict__ out)
{
    __shared__ float rh[28];
    __shared__ alignas(16) float qw_s[192];   // 16 ch x 12 (9 used + 3 pad)
    __shared__ alignas(16) float wv_s[192];
    __shared__ float r_s[RR * PW];   // X0, then r   (row M <-> image row vlo-1+M)
    __shared__ float va[RR * PW];    // X1, then v ping (v row L <-> image row vlo+L-1)
    __shared__ float vb[RR * PW];    // X2, then v pong

    const int b2   = blockIdx.x;
    const int b    = b2 >> 1;
    const int half = b2 & 1;
    const int vlo  = half ? 16 : 0;
    const int tid  = threadIdx.x;

    const float* X0 = layout  + (size_t)b * 2 * 4096;
    const float* X1 = X0 + 4096;
    const float* X2 = heatmap + (size_t)b * 4096;
    float* out_r = out + 1024 + (size_t)128 * 4096 + (size_t)b * 4096;
    float* out_h = out + 1024 + (size_t)256 * 4096 + (size_t)b * 4096;

    // stage weights into LDS, padded to 12/channel (pads zeroed, never used)
    if (tid < 192) {
        const int o = tid / 12, t = tid - o * 12;
        qw_s[tid] = (t < 9) ? q_w[o * 9 + t] : 0.f;
    } else if (tid < 384) {
        const int i2 = tid - 192;
        const int o = i2 / 12, t = i2 - o * 12;
        wv_s[i2] = (t < 9) ? w[o * 9 + t] : 0.f;
    }

    if (FIRST) {
        // ---- full prologue: border zero, stage X, collapse, r-conv ----
        for (int i = tid; i < 4 * PW; i += NT) {
            const int rr = (i < 2 * PW) ? (i / PW) : (48 + i / PW);  // 0,1,50,51
            const int cc = i % PW;
            const int idx = rr * PW + cc;
            r_s[idx] = 0.f; va[idx] = 0.f; vb[idx] = 0.f;
        }
        for (int i = tid; i < 2 * RR; i += NT) {
            const int rr = i >> 1, cc = (i & 1) ? (PW - 1) : 0;
            const int idx = rr * PW + cc;
            r_s[idx] = 0.f; va[idx] = 0.f; vb[idx] = 0.f;
        }
        __syncthreads();

        if (tid < 896) {
            const int coeff = tid >> 5, j = tid & 31;
            float s = 0.f;
            for (int c = j; c < 150; c += 32)
                s += r_w[c] * ((coeff < 27) ? h_w[c * 27 + coeff] : h_b[c]);
            s += __shfl_xor(s, 1, 32);  s += __shfl_xor(s, 2, 32);
            s += __shfl_xor(s, 4, 32);  s += __shfl_xor(s, 8, 32);
            s += __shfl_xor(s, 16, 32);
            if (j == 0) rh[coeff] = s;
        }
        for (int i = tid; i < RR * 64; i += NT) {
            const int M = i >> 6, col = i & 63;
            const int ir = vlo - 2 + M;
            if (ir >= 0 && ir < 64) {
                const int s = ir * 64 + col, d = M * PW + col + 1;
                r_s[d] = X0[s]; va[d] = X1[s]; vb[d] = X2[s];
            }
        }
        __syncthreads();  // X + rh + weights ready

        float rv[4];
        int   rpx[4];
        #pragma unroll
        for (int k2 = 0; k2 < 4; ++k2) {
            const int i = tid + k2 * NT;
            rpx[k2] = -1;
            if (i < 50 * 64) {
                const int row = i >> 6, col = i & 63;
                float acc = rh[27];
                #pragma unroll
                for (int dy = 0; dy < 3; ++dy)
                    #pragma unroll
                    for (int dx = 0; dx < 3; ++dx) {
                        const int idx = (row + dy) * PW + col + dx;
                        acc = fmaf(rh[0 * 9 + dy * 3 + dx], r_s[idx], acc);
                        acc = fmaf(rh[1 * 9 + dy * 3 + dx], va[idx],  acc);
                        acc = fmaf(rh[2 * 9 + dy * 3 + dx], vb[idx],  acc);
                    }
                const int ir = vlo - 1 + row;
                rv[k2]  = (ir >= 0 && ir < 64) ? acc : 0.f;  // true zero padding
                rpx[k2] = row * PW + col + 1;
            }
        }
        __syncthreads();  // X consumed

        // overwrite: r -> r_s; ring-zero v buffers
        for (int i = tid; i < 2 * PW + 96; i += NT) {
            int idx;
            if (i < 2 * PW) idx = ((i < PW) ? 0 : 49) * PW + (i % PW);
            else { const int k = i - 2 * PW; idx = (1 + (k >> 1)) * PW + ((k & 1) ? (PW - 1) : 0); }
            va[idx] = 0.f; vb[idx] = 0.f;
        }
        #pragma unroll
        for (int k2 = 0; k2 < 4; ++k2) if (rpx[k2] >= 0) r_s[rpx[k2]] = rv[k2];
        __syncthreads();  // r ready, v rings zero
    } else {
        // ---- slim prologue: r from out_r (bitwise-identical), v from vg ----
        // zero side cols of r_s rows 0..49; full ring of va/vb
        for (int i = tid; i < 100; i += NT) {
            const int rr = i >> 1, cc = (i & 1) ? (PW - 1) : 0;
            r_s[rr * PW + cc] = 0.f;
        }
        for (int i = tid; i < 2 * PW + 96; i += NT) {
            int idx;
            if (i < 2 * PW) idx = ((i < PW) ? 0 : 49) * PW + (i % PW);
            else { const int k = i - 2 * PW; idx = (1 + (k >> 1)) * PW + ((k & 1) ? (PW - 1) : 0); }
            va[idx] = 0.f; vb[idx] = 0.f;
        }
        // stage r interior rows 0..49 (0 outside image) + v rows 1..48
        for (int i = tid; i < 50 * 64; i += NT) {
            const int L = i >> 6, col = i & 63;
            const int ir = vlo - 1 + L;
            r_s[L * PW + col + 1] = (ir >= 0 && ir < 64) ? out_r[ir * 64 + col] : 0.f;
        }
        for (int i = tid; i < 48 * 64; i += NT) {
            const int L = (i >> 6) + 1, col = i & 63;
            va[L * PW + col + 1] = vg[b * 4096 + (vlo + L - 1) * 64 + col];
        }
        __syncthreads();  // r + v + weights ready
    }

    // per-lane geometry: one column, three cell rows, all 16 channels in-lane
    const int c  = tid & 63;        // image col (LDS col c+1)
    const int ty = tid >> 6;        // 0..15
    const int L0 = 1 + 3 * ty;      // first owned v row (LDS); window rows 3ty..3ty+4

    // rq[o*3+j] = conv3x3(r, q_w[o]) -> AGPRs; v0 = max_o rq if FIRST
    float rqa[48];
    {
        float rn[5][3];
        #pragma unroll
        for (int i = 0; i < 5; ++i)
            #pragma unroll
            for (int d = 0; d < 3; ++d)
                rn[i][d] = r_s[(3 * ty + i) * PW + c + d];
        float m0[3];
        #pragma unroll
        for (int o = 0; o < 16; ++o) {
            const float4 wa = *reinterpret_cast<const float4*>(qw_s + o * 12);
            const float4 wb = *reinterpret_cast<const float4*>(qw_s + o * 12 + 4);
            const float  w8 = qw_s[o * 12 + 8];
            #pragma unroll
            for (int j = 0; j < 3; ++j) {
                float q = 0.f;
                q = fmaf(wa.x, rn[j+0][0], q); q = fmaf(wa.y, rn[j+0][1], q); q = fmaf(wa.z, rn[j+0][2], q);
                q = fmaf(wa.w, rn[j+1][0], q); q = fmaf(wb.x, rn[j+1][1], q); q = fmaf(wb.y, rn[j+1][2], q);
                q = fmaf(wb.z, rn[j+2][0], q); q = fmaf(wb.w, rn[j+2][1], q); q = fmaf(w8,   rn[j+2][2], q);
                AW(rqa, o * 3 + j, q);
                m0[j] = (o == 0) ? q : fmaxf(m0[j], q);
            }
        }
        if (FIRST) {
            #pragma unroll
            for (int j = 0; j < 3; ++j)
                va[(L0 + j) * PW + c + 1] = m0[j];
        }
    }
    __syncthreads();  // v0 / staged v ready

    // NIT sweeps: 16 channels in-lane, weights via 16B LDS reads, rq via AGPR,
    // channel-paired max (clang fuses fmaxf(fmaxf(m,qa),qb) -> v_max3)
    float* vcur = va;
    float* vnxt = vb;
    #pragma unroll 1
    for (int it = 0; it < NIT; ++it) {
        float vn[5][3];
        #pragma unroll
        for (int i = 0; i < 5; ++i)
            #pragma unroll
            for (int d = 0; d < 3; ++d)
                vn[i][d] = vcur[(3 * ty + i) * PW + c + d];
        float m[3];
        {   // o = 0 (init)
            const float4 wa = *reinterpret_cast<const float4*>(wv_s);
            const float4 wb = *reinterpret_cast<const float4*>(wv_s + 4);
            const float  w8 = wv_s[8];
            #pragma unroll
            for (int j = 0; j < 3; ++j) {
                float q;
                AR(q, rqa, j);
                q = fmaf(wa.x, vn[j+0][0], q); q = fmaf(wa.y, vn[j+0][1], q); q = fmaf(wa.z, vn[j+0][2], q);
                q = fmaf(wa.w, vn[j+1][0], q); q = fmaf(wb.x, vn[j+1][1], q); q = fmaf(wb.y, vn[j+1][2], q);
                q = fmaf(wb.z, vn[j+2][0], q); q = fmaf(wb.w, vn[j+2][1], q); q = fmaf(w8,   vn[j+2][2], q);
                m[j] = q;
            }
        }
        #pragma unroll
        for (int ob = 1; ob < 15; ob += 2) {   // pairs (1,2)..(13,14)
            const float4 wa0 = *reinterpret_cast<const float4*>(wv_s + ob * 12);
            const float4 wb0 = *reinterpret_cast<const float4*>(wv_s + ob * 12 + 4);
            const float  w80 = wv_s[ob * 12 + 8];
            const float4 wa1 = *reinterpret_cast<const float4*>(wv_s + (ob + 1) * 12);
            const float4 wb1 = *reinterpret_cast<const float4*>(wv_s + (ob + 1) * 12 + 4);
            const float  w81 = wv_s[(ob + 1) * 12 + 8];
            #pragma unroll
            for (int j = 0; j < 3; ++j) {
                float qa, qb;
                AR(qa, rqa, ob * 3 + j);
                qa = fmaf(wa0.x, vn[j+0][0], qa); qa = fmaf(wa0.y, vn[j+0][1], qa); qa = fmaf(wa0.z, vn[j+0][2], qa);
                qa = fmaf(wa0.w, vn[j+1][0], qa); qa = fmaf(wb0.x, vn[j+1][1], qa); qa = fmaf(wb0.y, vn[j+1][2], qa);
                qa = fmaf(wb0.z, vn[j+2][0], qa); qa = fmaf(wb0.w, vn[j+2][1], qa); qa = fmaf(w80,   vn[j+2][2], qa);
                AR(qb, rqa, (ob + 1) * 3 + j);
                qb = fmaf(wa1.x, vn[j+0][0], qb); qb = fmaf(wa1.y, vn[j+0][1], qb); qb = fmaf(wa1.z, vn[j+0][2], qb);
                qb = fmaf(wa1.w, vn[j+1][0], qb); qb = fmaf(wb1.x, vn[j+1][1], qb); qb = fmaf(wb1.y, vn[j+1][2], qb);
                qb = fmaf(wb1.z, vn[j+2][0], qb); qb = fmaf(wb1.w, vn[j+2][1], qb); qb = fmaf(w81,   vn[j+2][2], qb);
                m[j] = fmaxf(fmaxf(m[j], qa), qb);   // -> v_max3
            }
        }
        {   // o = 15
            const float4 wa = *reinterpret_cast<const float4*>(wv_s + 15 * 12);
            const float4 wb = *reinterpret_cast<const float4*>(wv_s + 15 * 12 + 4);
            const float  w8 = wv_s[15 * 12 + 8];
            #pragma unroll
            for (int j = 0; j < 3; ++j) {
                float q;
                AR(q, rqa, 15 * 3 + j);
                q = fmaf(wa.x, vn[j+0][0], q); q = fmaf(wa.y, vn[j+0][1], q); q = fmaf(wa.z, vn[j+0][2], q);
                q = fmaf(wa.w, vn[j+1][0], q); q = fmaf(wb.x, vn[j+1][1], q); q = fmaf(wb.y, vn[j+1][2], q);
                q = fmaf(wb.z, vn[j+2][0], q); q = fmaf(wb.w, vn[j+2][1], q); q = fmaf(w8,   vn[j+2][2], q);
                m[j] = fmaxf(m[j], q);
            }
        }
        #pragma unroll
        for (int j = 0; j < 3; ++j)
            vnxt[(L0 + j) * PW + c + 1] = m[j];
        __syncthreads();
        float* t = vcur; vcur = vnxt; vnxt = t;
    }

    // writeback core rows (image half*32 .. half*32+31; L = ir - vlo + 1)
    if (!LAST) {
        for (int i = tid; i < 32 * 64; i += NT) {
            const int ir = half * 32 + (i >> 6), col = i & 63;
            vg[b * 4096 + ir * 64 + col] = vcur[(ir - vlo + 1) * PW + col + 1];
        }
    } else {
        float* out_v = out + 1024 + (size_t)b * 4096;
        for (int i = tid; i < 32 * 64; i += NT) {
            const int ir = half * 32 + (i >> 6), col = i & 63;
            out_v[ir * 64 + col] = vcur[(ir - vlo + 1) * PW + col + 1];
        }
    }
    if (FIRST) {
        for (int i = tid; i < 32 * 64; i += NT) {
            const int ir = half * 32 + (i >> 6), col = i & 63;
            out_r[ir * 64 + col] = r_s[(ir - vlo + 1) * PW + col + 1];
            out_h[ir * 64 + col] = X2[ir * 64 + col];
        }
    }

    if (LAST) {
        const int s1 = S1[b], s2 = S2[b];
        if ((s1 >> 5) == half && tid == 0) {
            float q16[16];
            #pragma unroll
            for (int o = 0; o < 16; ++o) {
                float acc = 0.f;
                #pragma unroll
                for (int dy = 0; dy < 3; ++dy)
                    #pragma unroll
                    for (int dx = 0; dx < 3; ++dx) {
                        const int li = (s1 + dy - vlo) * PW + s2 + dx;
                        acc = fmaf(qw_s[o * 12 + dy * 3 + dx], r_s[li], acc);
                        acc = fmaf(wv_s[o * 12 + dy * 3 + dx], vcur[li], acc);
                    }
                q16[o] = acc;
            }
            float lg[4];
            #pragma unroll
            for (int j = 0; j < 4; ++j) {
                float a = 0.f;
                #pragma unroll
                for (int o = 0; o < 16; ++o) a = fmaf(fc_w[j * 16 + o], q16[o], a);
                lg[j] = a;
            }
            const float m  = fmaxf(fmaxf(lg[0], lg[1]), fmaxf(lg[2], lg[3]));
            const float e0 = expf(lg[0] - m), e1 = expf(lg[1] - m);
            const float e2 = expf(lg[2] - m), e3 = expf(lg[3] - m);
            const float s  = e0 + e1 + e2 + e3;
            out[b * 4 + 0] = lg[0]; out[b * 4 + 1] = lg[1];
            out[b * 4 + 2] = lg[2]; out[b * 4 + 3] = lg[3];
            out[512 + b * 4 + 0] = e0 / s; out[512 + b * 4 + 1] = e1 / s;
            out[512 + b * 4 + 2] = e2 / s; out[512 + b * 4 + 3] = e3 / s;
        }
    }
}

extern "C" void kernel_launch(void* const* d_in, const int* in_sizes, int n_in,
                              void* d_out, int out_size, void* d_ws, size_t ws_size,
                              hipStream_t stream) {
    const float* layout  = (const float*)d_in[0];
    const float* heatmap = (const float*)d_in[1];
    const float* h_w     = (const float*)d_in[2];
    const float* h_b     = (const float*)d_in[3];
    const float* r_w     = (const float*)d_in[4];
    const float* q_w     = (const float*)d_in[5];
    const float* w       = (const float*)d_in[6];
    const float* fc_w    = (const float*)d_in[7];
    const int*   S1      = (const int*)d_in[8];
    const int*   S2      = (const int*)d_in[9];
    float* out = (float*)d_out;
    float* vg  = (float*)d_ws;   // 128*4096 f32 = 2 MB

    hipLaunchKernelGGL((vin_chunk<15, true,  false>), dim3(256), dim3(NT), 0, stream,
                       layout, heatmap, h_w, h_b, r_w, q_w, w, fc_w, S1, S2, vg, out);
    hipLaunchKernelGGL((vin_chunk<14, false, true>),  dim3(256), dim3(NT), 0, stream,
                       layout, heatmap, h_w, h_b, r_w, q_w, w, fc_w, S1, S2, vg, out);
}

// Round 17
// 102.538 us; speedup vs baseline: 1.0822x; 1.0822x over previous
//
#include <hip/hip_runtime.h>
#include <math.h>

#define NT 1024
#define PW 66      // padded LDS row stride
#define RR 52      // LDS buffer rows (52 X rows / 50 r rows / 48 v rows + ring)

// Pin to AGPR (unified file) — frees arch VGPRs for window/weights/temps.
#define AW(arr, idx, val) asm("v_accvgpr_write_b32 %0, %1" : "=a"(arr[idx]) : "v"(val))
#define AR(dst, arr, idx) asm("v_accvgpr_read_b32 %0, %1" : "=v"(dst) : "a"(arr[idx]))

// Two launches: chunk<15,FIRST> then chunk<14,LAST>. 256 blocks (1 per CU),
// block = half image (32 core rows + 16-row internal halo; 48 v-rows).
// Geometry (r15, best=105.5us): lane owns ONE column (c=tid&63) and THREE cell
// rows (ty=tid>>6), all 16 channels in-lane; weights in LDS (2xb128+b32 per
// channel); rq[48] AGPR-pinned; ONE channel's weights live at a time in the
// sweep loop (r16's max3 pairing doubled live weights -> shuttle, regressed).
// r17 delta vs r15: slim !FIRST prologue — stage r from out_r (bitwise-
// identical; launch 1 wrote it), skip X staging / collapse / r-conv / 2 barriers.
template<int NIT, bool FIRST, bool LAST>
__global__ __launch_bounds__(NT)
void vin_chunk(const float* __restrict__ layout,
               const float* __restrict__ heatmap,
               const float* __restrict__ h_w,
               const float* __restrict__ h_b,
               const float* __restrict__ r_w,
               const float* __restrict__ q_w,
               const float* __restrict__ w,
               const float* __restrict__ fc_w,
               const int* __restrict__ S1,
               const int* __restrict__ S2,
               float* __restrict__ vg,
               float* __restrict__ out)
{
    __shared__ float rh[28];
    __shared__ alignas(16) float qw_s[192];   // 16 ch x 12 (9 used + 3 pad)
    __shared__ alignas(16) float wv_s[192];
    __shared__ float r_s[RR * PW];   // X0, then r   (row M <-> image row vlo-1+M)
    __shared__ float va[RR * PW];    // X1, then v ping (v row L <-> image row vlo+L-1)
    __shared__ float vb[RR * PW];    // X2, then v pong

    const int b2   = blockIdx.x;
    const int b    = b2 >> 1;
    const int half = b2 & 1;
    const int vlo  = half ? 16 : 0;
    const int tid  = threadIdx.x;

    const float* X0 = layout  + (size_t)b * 2 * 4096;
    const float* X1 = X0 + 4096;
    const float* X2 = heatmap + (size_t)b * 4096;
    float* out_r = out + 1024 + (size_t)128 * 4096 + (size_t)b * 4096;
    float* out_h = out + 1024 + (size_t)256 * 4096 + (size_t)b * 4096;

    // stage weights into LDS, padded to 12/channel (pads zeroed, never used)
    if (tid < 192) {
        const int o = tid / 12, t = tid - o * 12;
        qw_s[tid] = (t < 9) ? q_w[o * 9 + t] : 0.f;
    } else if (tid < 384) {
        const int i2 = tid - 192;
        const int o = i2 / 12, t = i2 - o * 12;
        wv_s[i2] = (t < 9) ? w[o * 9 + t] : 0.f;
    }

    if (FIRST) {
        // ---- full prologue: border zero, stage X, collapse, r-conv ----
        for (int i = tid; i < 4 * PW; i += NT) {
            const int rr = (i < 2 * PW) ? (i / PW) : (48 + i / PW);  // 0,1,50,51
            const int cc = i % PW;
            const int idx = rr * PW + cc;
            r_s[idx] = 0.f; va[idx] = 0.f; vb[idx] = 0.f;
        }
        for (int i = tid; i < 2 * RR; i += NT) {
            const int rr = i >> 1, cc = (i & 1) ? (PW - 1) : 0;
            const int idx = rr * PW + cc;
            r_s[idx] = 0.f; va[idx] = 0.f; vb[idx] = 0.f;
        }
        __syncthreads();

        if (tid < 896) {
            const int coeff = tid >> 5, j = tid & 31;
            float s = 0.f;
            for (int c = j; c < 150; c += 32)
                s += r_w[c] * ((coeff < 27) ? h_w[c * 27 + coeff] : h_b[c]);
            s += __shfl_xor(s, 1, 32);  s += __shfl_xor(s, 2, 32);
            s += __shfl_xor(s, 4, 32);  s += __shfl_xor(s, 8, 32);
            s += __shfl_xor(s, 16, 32);
            if (j == 0) rh[coeff] = s;
        }
        for (int i = tid; i < RR * 64; i += NT) {
            const int M = i >> 6, col = i & 63;
            const int ir = vlo - 2 + M;
            if (ir >= 0 && ir < 64) {
                const int s = ir * 64 + col, d = M * PW + col + 1;
                r_s[d] = X0[s]; va[d] = X1[s]; vb[d] = X2[s];
            }
        }
        __syncthreads();  // X + rh + weights ready

        float rv[4];
        int   rpx[4];
        #pragma unroll
        for (int k2 = 0; k2 < 4; ++k2) {
            const int i = tid + k2 * NT;
            rpx[k2] = -1;
            if (i < 50 * 64) {
                const int row = i >> 6, col = i & 63;
                float acc = rh[27];
                #pragma unroll
                for (int dy = 0; dy < 3; ++dy)
                    #pragma unroll
                    for (int dx = 0; dx < 3; ++dx) {
                        const int idx = (row + dy) * PW + col + dx;
                        acc = fmaf(rh[0 * 9 + dy * 3 + dx], r_s[idx], acc);
                        acc = fmaf(rh[1 * 9 + dy * 3 + dx], va[idx],  acc);
                        acc = fmaf(rh[2 * 9 + dy * 3 + dx], vb[idx],  acc);
                    }
                const int ir = vlo - 1 + row;
                rv[k2]  = (ir >= 0 && ir < 64) ? acc : 0.f;  // true zero padding
                rpx[k2] = row * PW + col + 1;
            }
        }
        __syncthreads();  // X consumed

        // overwrite: r -> r_s; ring-zero v buffers
        for (int i = tid; i < 2 * PW + 96; i += NT) {
            int idx;
            if (i < 2 * PW) idx = ((i < PW) ? 0 : 49) * PW + (i % PW);
            else { const int k = i - 2 * PW; idx = (1 + (k >> 1)) * PW + ((k & 1) ? (PW - 1) : 0); }
            va[idx] = 0.f; vb[idx] = 0.f;
        }
        #pragma unroll
        for (int k2 = 0; k2 < 4; ++k2) if (rpx[k2] >= 0) r_s[rpx[k2]] = rv[k2];
        __syncthreads();  // r ready, v rings zero
    } else {
        // ---- slim prologue: r from out_r (bitwise-identical), v from vg ----
        for (int i = tid; i < 100; i += NT) {
            const int rr = i >> 1, cc = (i & 1) ? (PW - 1) : 0;
            r_s[rr * PW + cc] = 0.f;
        }
        for (int i = tid; i < 2 * PW + 96; i += NT) {
            int idx;
            if (i < 2 * PW) idx = ((i < PW) ? 0 : 49) * PW + (i % PW);
            else { const int k = i - 2 * PW; idx = (1 + (k >> 1)) * PW + ((k & 1) ? (PW - 1) : 0); }
            va[idx] = 0.f; vb[idx] = 0.f;
        }
        for (int i = tid; i < 50 * 64; i += NT) {
            const int L = i >> 6, col = i & 63;
            const int ir = vlo - 1 + L;
            r_s[L * PW + col + 1] = (ir >= 0 && ir < 64) ? out_r[ir * 64 + col] : 0.f;
        }
        for (int i = tid; i < 48 * 64; i += NT) {
            const int L = (i >> 6) + 1, col = i & 63;
            va[L * PW + col + 1] = vg[b * 4096 + (vlo + L - 1) * 64 + col];
        }
        __syncthreads();  // r + v + weights ready
    }

    // per-lane geometry: one column, three cell rows, all 16 channels in-lane
    const int c  = tid & 63;        // image col (LDS col c+1)
    const int ty = tid >> 6;        // 0..15
    const int L0 = 1 + 3 * ty;      // first owned v row (LDS); window rows 3ty..3ty+4

    // rq[o*3+j] = conv3x3(r, q_w[o]) -> AGPRs; v0 = max_o rq if FIRST
    float rqa[48];
    {
        float rn[5][3];
        #pragma unroll
        for (int i = 0; i < 5; ++i)
            #pragma unroll
            for (int d = 0; d < 3; ++d)
                rn[i][d] = r_s[(3 * ty + i) * PW + c + d];
        float m0[3];
        #pragma unroll
        for (int o = 0; o < 16; ++o) {
            const float4 wa = *reinterpret_cast<const float4*>(qw_s + o * 12);
            const float4 wb = *reinterpret_cast<const float4*>(qw_s + o * 12 + 4);
            const float  w8 = qw_s[o * 12 + 8];
            #pragma unroll
            for (int j = 0; j < 3; ++j) {
                float q = 0.f;
                q = fmaf(wa.x, rn[j+0][0], q); q = fmaf(wa.y, rn[j+0][1], q); q = fmaf(wa.z, rn[j+0][2], q);
                q = fmaf(wa.w, rn[j+1][0], q); q = fmaf(wb.x, rn[j+1][1], q); q = fmaf(wb.y, rn[j+1][2], q);
                q = fmaf(wb.z, rn[j+2][0], q); q = fmaf(wb.w, rn[j+2][1], q); q = fmaf(w8,   rn[j+2][2], q);
                AW(rqa, o * 3 + j, q);
                m0[j] = (o == 0) ? q : fmaxf(m0[j], q);
            }
        }
        if (FIRST) {
            #pragma unroll
            for (int j = 0; j < 3; ++j)
                va[(L0 + j) * PW + c + 1] = m0[j];
        }
    }
    __syncthreads();  // v0 / staged v ready

    // NIT sweeps: 16 channels in-lane, weights via 16B LDS reads, rq via AGPR
    float* vcur = va;
    float* vnxt = vb;
    #pragma unroll 1
    for (int it = 0; it < NIT; ++it) {
        float vn[5][3];
        #pragma unroll
        for (int i = 0; i < 5; ++i)
            #pragma unroll
            for (int d = 0; d < 3; ++d)
                vn[i][d] = vcur[(3 * ty + i) * PW + c + d];
        float m[3];
        #pragma unroll
        for (int o = 0; o < 16; ++o) {
            const float4 wa = *reinterpret_cast<const float4*>(wv_s + o * 12);
            const float4 wb = *reinterpret_cast<const float4*>(wv_s + o * 12 + 4);
            const float  w8 = wv_s[o * 12 + 8];
            #pragma unroll
            for (int j = 0; j < 3; ++j) {
                float q;
                AR(q, rqa, o * 3 + j);
                q = fmaf(wa.x, vn[j+0][0], q); q = fmaf(wa.y, vn[j+0][1], q); q = fmaf(wa.z, vn[j+0][2], q);
                q = fmaf(wa.w, vn[j+1][0], q); q = fmaf(wb.x, vn[j+1][1], q); q = fmaf(wb.y, vn[j+1][2], q);
                q = fmaf(wb.z, vn[j+2][0], q); q = fmaf(wb.w, vn[j+2][1], q); q = fmaf(w8,   vn[j+2][2], q);
                m[j] = (o == 0) ? q : fmaxf(m[j], q);
            }
        }
        #pragma unroll
        for (int j = 0; j < 3; ++j)
            vnxt[(L0 + j) * PW + c + 1] = m[j];
        __syncthreads();
        float* t = vcur; vcur = vnxt; vnxt = t;
    }

    // writeback core rows (image half*32 .. half*32+31; L = ir - vlo + 1)
    if (!LAST) {
        for (int i = tid; i < 32 * 64; i += NT) {
            const int ir = half * 32 + (i >> 6), col = i & 63;
            vg[b * 4096 + ir * 64 + col] = vcur[(ir - vlo + 1) * PW + col + 1];
        }
    } else {
        float* out_v = out + 1024 + (size_t)b * 4096;
        for (int i = tid; i < 32 * 64; i += NT) {
            const int ir = half * 32 + (i >> 6), col = i & 63;
            out_v[ir * 64 + col] = vcur[(ir - vlo + 1) * PW + col + 1];
        }
    }
    if (FIRST) {
        for (int i = tid; i < 32 * 64; i += NT) {
            const int ir = half * 32 + (i >> 6), col = i & 63;
            out_r[ir * 64 + col] = r_s[(ir - vlo + 1) * PW + col + 1];
            out_h[ir * 64 + col] = X2[ir * 64 + col];
        }
    }

    if (LAST) {
        const int s1 = S1[b], s2 = S2[b];
        if ((s1 >> 5) == half && tid == 0) {
            float q16[16];
            #pragma unroll
            for (int o = 0; o < 16; ++o) {
                float acc = 0.f;
                #pragma unroll
                for (int dy = 0; dy < 3; ++dy)
                    #pragma unroll
                    for (int dx = 0; dx < 3; ++dx) {
                        const int li = (s1 + dy - vlo) * PW + s2 + dx;
                        acc = fmaf(qw_s[o * 12 + dy * 3 + dx], r_s[li], acc);
                        acc = fmaf(wv_s[o * 12 + dy * 3 + dx], vcur[li], acc);
                    }
                q16[o] = acc;
            }
            float lg[4];
            #pragma unroll
            for (int j = 0; j < 4; ++j) {
                float a = 0.f;
                #pragma unroll
                for (int o = 0; o < 16; ++o) a = fmaf(fc_w[j * 16 + o], q16[o], a);
                lg[j] = a;
            }
            const float m  = fmaxf(fmaxf(lg[0], lg[1]), fmaxf(lg[2], lg[3]));
            const float e0 = expf(lg[0] - m), e1 = expf(lg[1] - m);
            const float e2 = expf(lg[2] - m), e3 = expf(lg[3] - m);
            const float s  = e0 + e1 + e2 + e3;
            out[b * 4 + 0] = lg[0]; out[b * 4 + 1] = lg[1];
            out[b * 4 + 2] = lg[2]; out[b * 4 + 3] = lg[3];
            out[512 + b * 4 + 0] = e0 / s; out[512 + b * 4 + 1] = e1 / s;
            out[512 + b * 4 + 2] = e2 / s; out[512 + b * 4 + 3] = e3 / s;
        }
    }
}

extern "C" void kernel_launch(void* const* d_in, const int* in_sizes, int n_in,
                              void* d_out, int out_size, void* d_ws, size_t ws_size,
                              hipStream_t stream) {
    const float* layout  = (const float*)d_in[0];
    const float* heatmap = (const float*)d_in[1];
    const float* h_w     = (const float*)d_in[2];
    const float* h_b     = (const float*)d_in[3];
    const float* r_w     = (const float*)d_in[4];
    const float* q_w     = (const float*)d_in[5];
    const float* w       = (const float*)d_in[6];
    const float* fc_w    = (const float*)d_in[7];
    const int*   S1      = (const int*)d_in[8];
    const int*   S2      = (const int*)d_in[9];
    float* out = (float*)d_out;
    float* vg  = (float*)d_ws;   // 128*4096 f32 = 2 MB

    hipLaunchKernelGGL((vin_chunk<15, true,  false>), dim3(256), dim3(NT), 0, stream,
                       layout, heatmap, h_w, h_b, r_w, q_w, w, fc_w, S1, S2, vg, out);
    hipLaunchKernelGGL((vin_chunk<14, false, true>),  dim3(256), dim3(NT), 0, stream,
                       layout, heatmap, h_w, h_b, r_w, q_w, w, fc_w, S1, S2, vg, out);
}

// Round 18
// 101.367 us; speedup vs baseline: 1.0947x; 1.0115x over previous
//
#include <hip/hip_runtime.h>
#include <math.h>

#define NT 1024
#define PW 66      // padded LDS row stride
#define RR 52      // LDS buffer rows (52 X rows / 50 r rows / 48 v rows + ring)

typedef float v2f __attribute__((ext_vector_type(2)));
#define SP(x) ((v2f){(x), (x)})   // splat scalar into both pk halves

// Pin to AGPR (unified file) — frees arch VGPRs for window/weights/temps.
#define AW(arr, idx, val) asm("v_accvgpr_write_b32 %0, %1" : "=a"(arr[idx]) : "v"(val))
#define AR(dst, arr, idx) asm("v_accvgpr_read_b32 %0, %1" : "=v"(dst) : "a"(arr[idx]))

// Two launches: chunk<15,FIRST> then chunk<14,LAST>. 256 blocks (1 per CU),
// block = half image (32 core rows + 16-row internal halo; 48 v-rows).
// Geometry (r15/r17): lane owns ONE column (c=tid&63) and THREE cell rows
// (ty=tid>>6), all 16 channels in-lane; rq[48] AGPR-pinned; slim !FIRST
// prologue (r from out_r, bitwise-identical).
// r18 delta: CHANNEL-PAIR PACKED MATH — weights pre-interleaved in LDS as
// float2 {w[2p][t], w[2p+1][t]} (12-tap padded); inner loop uses
// v_pk_fma_f32 / v_pk_max_f32 via <2 x float> builtins. Data operand is a
// splat (same value both halves). FMA instr 432->216, max 45->27 per
// lane-sweep; max association changes only (exact); per-channel FMA order
// unchanged -> absmax identical.
template<int NIT, bool FIRST, bool LAST>
__global__ __launch_bounds__(NT)
void vin_chunk(const float* __restrict__ layout,
               const float* __restrict__ heatmap,
               const float* __restrict__ h_w,
               const float* __restrict__ h_b,
               const float* __restrict__ r_w,
               const float* __restrict__ q_w,
               const float* __restrict__ w,
               const float* __restrict__ fc_w,
               const int* __restrict__ S1,
               const int* __restrict__ S2,
               float* __restrict__ vg,
               float* __restrict__ out)
{
    __shared__ float rh[28];
    // pair p = channels (2p, 2p+1); layout [p][tap][half], 12 taps (9 used)
    __shared__ alignas(16) float qw_s[192];
    __shared__ alignas(16) float wv_s[192];
    __shared__ float r_s[RR * PW];   // X0, then r   (row M <-> image row vlo-1+M)
    __shared__ float va[RR * PW];    // X1, then v ping (v row L <-> image row vlo+L-1)
    __shared__ float vb[RR * PW];    // X2, then v pong

    const int b2   = blockIdx.x;
    const int b    = b2 >> 1;
    const int half = b2 & 1;
    const int vlo  = half ? 16 : 0;
    const int tid  = threadIdx.x;

    const float* X0 = layout  + (size_t)b * 2 * 4096;
    const float* X1 = X0 + 4096;
    const float* X2 = heatmap + (size_t)b * 4096;
    float* out_r = out + 1024 + (size_t)128 * 4096 + (size_t)b * 4096;
    float* out_h = out + 1024 + (size_t)256 * 4096 + (size_t)b * 4096;

    // stage weights into LDS, channel-pair interleaved, 12-tap padded
    if (tid < 192) {
        const int p = tid / 24, rem = tid - p * 24, t = rem >> 1, hf = rem & 1;
        qw_s[tid] = (t < 9) ? q_w[(2 * p + hf) * 9 + t] : 0.f;
    } else if (tid < 384) {
        const int i2 = tid - 192;
        const int p = i2 / 24, rem = i2 - p * 24, t = rem >> 1, hf = rem & 1;
        wv_s[i2] = (t < 9) ? w[(2 * p + hf) * 9 + t] : 0.f;
    }

    if (FIRST) {
        // ---- full prologue: border zero, stage X, collapse, r-conv ----
        for (int i = tid; i < 4 * PW; i += NT) {
            const int rr = (i < 2 * PW) ? (i / PW) : (48 + i / PW);  // 0,1,50,51
            const int cc = i % PW;
            const int idx = rr * PW + cc;
            r_s[idx] = 0.f; va[idx] = 0.f; vb[idx] = 0.f;
        }
        for (int i = tid; i < 2 * RR; i += NT) {
            const int rr = i >> 1, cc = (i & 1) ? (PW - 1) : 0;
            const int idx = rr * PW + cc;
            r_s[idx] = 0.f; va[idx] = 0.f; vb[idx] = 0.f;
        }
        __syncthreads();

        if (tid < 896) {
            const int coeff = tid >> 5, j = tid & 31;
            float s = 0.f;
            for (int c = j; c < 150; c += 32)
                s += r_w[c] * ((coeff < 27) ? h_w[c * 27 + coeff] : h_b[c]);
            s += __shfl_xor(s, 1, 32);  s += __shfl_xor(s, 2, 32);
            s += __shfl_xor(s, 4, 32);  s += __shfl_xor(s, 8, 32);
            s += __shfl_xor(s, 16, 32);
            if (j == 0) rh[coeff] = s;
        }
        for (int i = tid; i < RR * 64; i += NT) {
            const int M = i >> 6, col = i & 63;
            const int ir = vlo - 2 + M;
            if (ir >= 0 && ir < 64) {
                const int s = ir * 64 + col, d = M * PW + col + 1;
                r_s[d] = X0[s]; va[d] = X1[s]; vb[d] = X2[s];
            }
        }
        __syncthreads();  // X + rh + weights ready

        float rv[4];
        int   rpx[4];
        #pragma unroll
        for (int k2 = 0; k2 < 4; ++k2) {
            const int i = tid + k2 * NT;
            rpx[k2] = -1;
            if (i < 50 * 64) {
                const int row = i >> 6, col = i & 63;
                float acc = rh[27];
                #pragma unroll
                for (int dy = 0; dy < 3; ++dy)
                    #pragma unroll
                    for (int dx = 0; dx < 3; ++dx) {
                        const int idx = (row + dy) * PW + col + dx;
                        acc = fmaf(rh[0 * 9 + dy * 3 + dx], r_s[idx], acc);
                        acc = fmaf(rh[1 * 9 + dy * 3 + dx], va[idx],  acc);
                        acc = fmaf(rh[2 * 9 + dy * 3 + dx], vb[idx],  acc);
                    }
                const int ir = vlo - 1 + row;
                rv[k2]  = (ir >= 0 && ir < 64) ? acc : 0.f;  // true zero padding
                rpx[k2] = row * PW + col + 1;
            }
        }
        __syncthreads();  // X consumed

        // overwrite: r -> r_s; ring-zero v buffers
        for (int i = tid; i < 2 * PW + 96; i += NT) {
            int idx;
            if (i < 2 * PW) idx = ((i < PW) ? 0 : 49) * PW + (i % PW);
            else { const int k = i - 2 * PW; idx = (1 + (k >> 1)) * PW + ((k & 1) ? (PW - 1) : 0); }
            va[idx] = 0.f; vb[idx] = 0.f;
        }
        #pragma unroll
        for (int k2 = 0; k2 < 4; ++k2) if (rpx[k2] >= 0) r_s[rpx[k2]] = rv[k2];
        __syncthreads();  // r ready, v rings zero
    } else {
        // ---- slim prologue: r from out_r (bitwise-identical), v from vg ----
        for (int i = tid; i < 100; i += NT) {
            const int rr = i >> 1, cc = (i & 1) ? (PW - 1) : 0;
            r_s[rr * PW + cc] = 0.f;
        }
        for (int i = tid; i < 2 * PW + 96; i += NT) {
            int idx;
            if (i < 2 * PW) idx = ((i < PW) ? 0 : 49) * PW + (i % PW);
            else { const int k = i - 2 * PW; idx = (1 + (k >> 1)) * PW + ((k & 1) ? (PW - 1) : 0); }
            va[idx] = 0.f; vb[idx] = 0.f;
        }
        for (int i = tid; i < 50 * 64; i += NT) {
            const int L = i >> 6, col = i & 63;
            const int ir = vlo - 1 + L;
            r_s[L * PW + col + 1] = (ir >= 0 && ir < 64) ? out_r[ir * 64 + col] : 0.f;
        }
        for (int i = tid; i < 48 * 64; i += NT) {
            const int L = (i >> 6) + 1, col = i & 63;
            va[L * PW + col + 1] = vg[b * 4096 + (vlo + L - 1) * 64 + col];
        }
        __syncthreads();  // r + v + weights ready
    }

    // per-lane geometry: one column, three cell rows, all 16 channels in-lane
    const int c  = tid & 63;        // image col (LDS col c+1)
    const int ty = tid >> 6;        // 0..15
    const int L0 = 1 + 3 * ty;      // first owned v row (LDS); window rows 3ty..3ty+4

    // rq (channel-pair packed) -> AGPRs; v0 = max over channels if FIRST
    // rqa layout: [p][j][half]: idx = p*6 + j*2 + half
    float rqa[48];
    {
        float rn[5][3];
        #pragma unroll
        for (int i = 0; i < 5; ++i)
            #pragma unroll
            for (int d = 0; d < 3; ++d)
                rn[i][d] = r_s[(3 * ty + i) * PW + c + d];
        v2f m0[3];
        #pragma unroll
        for (int p = 0; p < 8; ++p) {
            const v2f* wp = reinterpret_cast<const v2f*>(qw_s + p * 24);
            const v2f w0 = wp[0], w1 = wp[1], w2 = wp[2];
            const v2f w3 = wp[3], w4 = wp[4], w5 = wp[5];
            const v2f w6 = wp[6], w7 = wp[7], w8 = wp[8];
            #pragma unroll
            for (int j = 0; j < 3; ++j) {
                v2f q = {0.f, 0.f};
                q = __builtin_elementwise_fma(w0, SP(rn[j+0][0]), q);
                q = __builtin_elementwise_fma(w1, SP(rn[j+0][1]), q);
                q = __builtin_elementwise_fma(w2, SP(rn[j+0][2]), q);
                q = __builtin_elementwise_fma(w3, SP(rn[j+1][0]), q);
                q = __builtin_elementwise_fma(w4, SP(rn[j+1][1]), q);
                q = __builtin_elementwise_fma(w5, SP(rn[j+1][2]), q);
                q = __builtin_elementwise_fma(w6, SP(rn[j+2][0]), q);
                q = __builtin_elementwise_fma(w7, SP(rn[j+2][1]), q);
                q = __builtin_elementwise_fma(w8, SP(rn[j+2][2]), q);
                AW(rqa, p * 6 + j * 2 + 0, q.x);
                AW(rqa, p * 6 + j * 2 + 1, q.y);
                m0[j] = (p == 0) ? q : __builtin_elementwise_max(m0[j], q);
            }
        }
        if (FIRST) {
            #pragma unroll
            for (int j = 0; j < 3; ++j)
                va[(L0 + j) * PW + c + 1] = fmaxf(m0[j].x, m0[j].y);
        }
    }
    __syncthreads();  // v0 / staged v ready

    // NIT sweeps: channel-pair pk math; weights via b128 LDS reads; rq via AGPR
    float* vcur = va;
    float* vnxt = vb;
    #pragma unroll 1
    for (int it = 0; it < NIT; ++it) {
        float vn[5][3];
        #pragma unroll
        for (int i = 0; i < 5; ++i)
            #pragma unroll
            for (int d = 0; d < 3; ++d)
                vn[i][d] = vcur[(3 * ty + i) * PW + c + d];
        v2f mp[3];
        #pragma unroll
        for (int p = 0; p < 8; ++p) {
            const v2f* wp = reinterpret_cast<const v2f*>(wv_s + p * 24);
            const v2f w0 = wp[0], w1 = wp[1], w2 = wp[2];
            const v2f w3 = wp[3], w4 = wp[4], w5 = wp[5];
            const v2f w6 = wp[6], w7 = wp[7], w8 = wp[8];
            #pragma unroll
            for (int j = 0; j < 3; ++j) {
                float qlo, qhi;
                AR(qlo, rqa, p * 6 + j * 2 + 0);
                AR(qhi, rqa, p * 6 + j * 2 + 1);
                v2f q; q.x = qlo; q.y = qhi;
                q = __builtin_elementwise_fma(w0, SP(vn[j+0][0]), q);
                q = __builtin_elementwise_fma(w1, SP(vn[j+0][1]), q);
                q = __builtin_elementwise_fma(w2, SP(vn[j+0][2]), q);
                q = __builtin_elementwise_fma(w3, SP(vn[j+1][0]), q);
                q = __builtin_elementwise_fma(w4, SP(vn[j+1][1]), q);
                q = __builtin_elementwise_fma(w5, SP(vn[j+1][2]), q);
                q = __builtin_elementwise_fma(w6, SP(vn[j+2][0]), q);
                q = __builtin_elementwise_fma(w7, SP(vn[j+2][1]), q);
                q = __builtin_elementwise_fma(w8, SP(vn[j+2][2]), q);
                mp[j] = (p == 0) ? q : __builtin_elementwise_max(mp[j], q);
            }
        }
        #pragma unroll
        for (int j = 0; j < 3; ++j)
            vnxt[(L0 + j) * PW + c + 1] = fmaxf(mp[j].x, mp[j].y);
        __syncthreads();
        float* t = vcur; vcur = vnxt; vnxt = t;
    }

    // writeback core rows (image half*32 .. half*32+31; L = ir - vlo + 1)
    if (!LAST) {
        for (int i = tid; i < 32 * 64; i += NT) {
            const int ir = half * 32 + (i >> 6), col = i & 63;
            vg[b * 4096 + ir * 64 + col] = vcur[(ir - vlo + 1) * PW + col + 1];
        }
    } else {
        float* out_v = out + 1024 + (size_t)b * 4096;
        for (int i = tid; i < 32 * 64; i += NT) {
            const int ir = half * 32 + (i >> 6), col = i & 63;
            out_v[ir * 64 + col] = vcur[(ir - vlo + 1) * PW + col + 1];
        }
    }
    if (FIRST) {
        for (int i = tid; i < 32 * 64; i += NT) {
            const int ir = half * 32 + (i >> 6), col = i & 63;
            out_r[ir * 64 + col] = r_s[(ir - vlo + 1) * PW + col + 1];
            out_h[ir * 64 + col] = X2[ir * 64 + col];
        }
    }

    if (LAST) {
        const int s1 = S1[b], s2 = S2[b];
        if ((s1 >> 5) == half && tid == 0) {
            float q16[16];
            #pragma unroll
            for (int o = 0; o < 16; ++o) {
                const int base = (o >> 1) * 24 + (o & 1);   // packed layout
                float acc = 0.f;
                #pragma unroll
                for (int dy = 0; dy < 3; ++dy)
                    #pragma unroll
                    for (int dx = 0; dx < 3; ++dx) {
                        const int li = (s1 + dy - vlo) * PW + s2 + dx;
                        const int t  = dy * 3 + dx;
                        acc = fmaf(qw_s[base + t * 2], r_s[li], acc);
                        acc = fmaf(wv_s[base + t * 2], vcur[li], acc);
                    }
                q16[o] = acc;
            }
            float lg[4];
            #pragma unroll
            for (int j = 0; j < 4; ++j) {
                float a = 0.f;
                #pragma unroll
                for (int o = 0; o < 16; ++o) a = fmaf(fc_w[j * 16 + o], q16[o], a);
                lg[j] = a;
            }
            const float m  = fmaxf(fmaxf(lg[0], lg[1]), fmaxf(lg[2], lg[3]));
            const float e0 = expf(lg[0] - m), e1 = expf(lg[1] - m);
            const float e2 = expf(lg[2] - m), e3 = expf(lg[3] - m);
            const float s  = e0 + e1 + e2 + e3;
            out[b * 4 + 0] = lg[0]; out[b * 4 + 1] = lg[1];
            out[b * 4 + 2] = lg[2]; out[b * 4 + 3] = lg[3];
            out[512 + b * 4 + 0] = e0 / s; out[512 + b * 4 + 1] = e1 / s;
            out[512 + b * 4 + 2] = e2 / s; out[512 + b * 4 + 3] = e3 / s;
        }
    }
}

extern "C" void kernel_launch(void* const* d_in, const int* in_sizes, int n_in,
                              void* d_out, int out_size, void* d_ws, size_t ws_size,
                              hipStream_t stream) {
    const float* layout  = (const float*)d_in[0];
    const float* heatmap = (const float*)d_in[1];
    const float* h_w     = (const float*)d_in[2];
    const float* h_b     = (const float*)d_in[3];
    const float* r_w     = (const float*)d_in[4];
    const float* q_w     = (const float*)d_in[5];
    const float* w       = (const float*)d_in[6];
    const float* fc_w    = (const float*)d_in[7];
    const int*   S1      = (const int*)d_in[8];
    const int*   S2      = (const int*)d_in[9];
    float* out = (float*)d_out;
    float* vg  = (float*)d_ws;   // 128*4096 f32 = 2 MB

    hipLaunchKernelGGL((vin_chunk<15, true,  false>), dim3(256), dim3(NT), 0, stream,
                       layout, heatmap, h_w, h_b, r_w, q_w, w, fc_w, S1, S2, vg, out);
    hipLaunchKernelGGL((vin_chunk<14, false, true>),  dim3(256), dim3(NT), 0, stream,
                       layout, heatmap, h_w, h_b, r_w, q_w, w, fc_w, S1, S2, vg, out);
}